// Round 2
// baseline (245.490 us; speedup 1.0000x reference)
//
#include <hip/hip_runtime.h>

typedef __bf16 bf16x8 __attribute__((ext_vector_type(8)));
typedef __bf16 bf16x4 __attribute__((ext_vector_type(4)));
typedef float  f32x4  __attribute__((ext_vector_type(4)));

#define MFMA16(a, b, c) __builtin_amdgcn_mfma_f32_16x16x32_bf16(a, b, c, 0, 0, 0)
// async global->LDS, 16B per lane; LDS dest = wave-uniform base + lane*16
#define GLL(gp, lp) __builtin_amdgcn_global_load_lds( \
    (__attribute__((address_space(1))) void*)(gp),    \
    (__attribute__((address_space(3))) void*)(lp), 16, 0, 0)
#define WAITBAR(N) asm volatile("s_waitcnt vmcnt(" #N ") lgkmcnt(0)\n\ts_barrier" ::: "memory")
// 8-phase barriers: BAR1 plain; BAR2 retires this wave's ds_reads before any
// wave can issue next phase's GLLs into the region (WAR safety, rule #18);
// VBAR1 = counted vmcnt (4 GLLs = 2 half-tiles stay in flight across it).
#define BAR1()  asm volatile("s_barrier" ::: "memory")
#define BAR2()  asm volatile("s_waitcnt lgkmcnt(0)\n\ts_barrier" ::: "memory")
#define VBAR1() asm volatile("s_waitcnt vmcnt(4)\n\ts_barrier" ::: "memory")

// ---------------- cast fp32 -> bf16 (vectorized) ----------------
__global__ __launch_bounds__(256) void cast_x_kernel(const float* __restrict__ in,
                                                     __bf16* __restrict__ out) {
  int i = blockIdx.x * 256 + threadIdx.x;
  const float4 v = ((const float4*)in)[i];
  bf16x4 o = {(__bf16)v.x, (__bf16)v.y, (__bf16)v.z, (__bf16)v.w};
  ((bf16x4*)out)[i] = o;
}

// ---------------- transpose + cast: out[n][k] = (bf16)in[k][n] ----------------
__global__ void transpose_cast_kernel(const float* __restrict__ in,
                                      __bf16* __restrict__ out,
                                      int rows, int cols) {
  __shared__ float tile[32][33];
  int tx = threadIdx.x, ty = threadIdx.y;
  int x = blockIdx.x * 32 + tx;
  int y0 = blockIdx.y * 32;
#pragma unroll
  for (int i = 0; i < 32; i += 8)
    tile[ty + i][tx] = in[(y0 + ty + i) * cols + x];
  __syncthreads();
  int ox = y0 + tx;
  int oy0 = blockIdx.x * 32;
#pragma unroll
  for (int i = 0; i < 32; i += 8)
    out[(oy0 + ty + i) * rows + ox] = (__bf16)tile[tx][ty + i];
}

#define QSCALE 0.045084220027780106f

// ======= QKV GEMM: 256x256 tile, BK=64, 8-phase counted-vmcnt schedule =======
// C[8192,3072] = A[8192,1024] * Bt[3072,1024]^T, epilogue scatters Q/K/V.
// 512 thr = 8 waves (2M x 4N), wave tile 128x64, acc = 8x4 f32x4 = 128 VGPR.
// LDS 128 KiB: A[2buf][2half][128x64] | B same at +32768 elems.
// LDS layout: 16x32-elem subtiles (1024 B), byte^=((byte>>9)&1)<<5 (st_16x32).
// GLL writes linearly -> global SOURCE is pre-swizzled (rule #21).
// Phases (per iter = K-tiles T0=2i [buf0], T1=2i+1 [buf1]):
//  ph1 rdA03(b0)+rdB01(b0), stage Ah0(T1);  mma m0n0
//  ph2 rdB23(b0),           stage Ah1(T1);  mma m0n1
//  ph3 rdA47(b0),           stage Bh0(T2);  mma m1n0
//  ph4                      stage Bh1(T2);  VBAR; mma m1n1
//  ph5-8: same on buf1/T1, staging Ah*(T2), Bh*(T3).
// vmcnt(4) at ph4/ph8 guarantees (in-order retire, m135) every half-tile is
// globally complete >=1 barrier before its first ds_read.
__global__ __launch_bounds__(512) void gemm256_qkv(
    const __bf16* __restrict__ A, const __bf16* __restrict__ Bt,
    __bf16* __restrict__ qo, __bf16* __restrict__ ko, __bf16* __restrict__ vo) {
  __shared__ __bf16 LDS[65536];  // 128 KiB
  const int tid = threadIdx.x;
  const int w = tid >> 6, lane = tid & 63;
  const int quad = lane >> 4, l15 = lane & 15;
  const int wr = w >> 2, wc = w & 3;
  // grid: 384 blocks; each XCD owns 4 contiguous m-rows (A 2MB L2-resident)
  const int g = (blockIdx.x & 7) * 48 + (blockIdx.x >> 3);
  const int by = g / 12, bx = g - by * 12;
  const int m0 = by * 256, n0 = bx * 256;

  // staging source (pre-swizzled): lane l of (wave w, inst i) supplies
  // row = w*16 + (l>>2), col granule = ((l&3) ^ ((l>>5)<<1)) + i*4
  const int srow = w * 16 + (lane >> 2);
  const int scg = (((lane & 3) ^ (((lane >> 5) & 1) << 1))) * 8;
  const __bf16* ag = A + (m0 + srow) * 1024 + scg;
  const __bf16* bg = Bt + (n0 + srow) * 1024 + scg;

  auto stageA = [&](int t, int h, int bufo) {
    const __bf16* gp = ag + h * 131072 + t * 64;
    __bf16* lp = (__bf16*)LDS + bufo + h * 8192 + w * 1024;
    GLL(gp, lp);
    GLL(gp + 32, lp + 512);
  };
  auto stageB = [&](int t, int h, int bufo) {
    const __bf16* gp = bg + h * 131072 + t * 64;
    __bf16* lp = (__bf16*)LDS + 32768 + bufo + h * 8192 + w * 1024;
    GLL(gp, lp);
    GLL(gp + 32, lp + 512);
  };

  // fragment read bases (swizzled): elem = sub*512 + l15*32 + swq2
  const int swq2 = (quad * 8) ^ ((l15 >> 3) << 4);
  const __bf16* Ard = LDS + wr * 8192 + l15 * 32 + swq2;
  const __bf16* Brd = LDS + 32768 + (wc >> 1) * 8192 + (wc & 1) * 4096 + l15 * 32 + swq2;

  f32x4 acc[8][4] = {};
  bf16x8 a[4][2], bA[2][2], bB[2][2];

  auto rdA = [&](int bufo, int i0) {
#pragma unroll
    for (int i = 0; i < 4; ++i)
#pragma unroll
      for (int ks = 0; ks < 2; ++ks)
        a[i][ks] = *(const bf16x8*)(Ard + bufo + ((i0 + i) * 2 + ks) * 512);
  };
  auto rdB = [&](int bufo, int j0, bf16x8 (&bb)[2][2]) {
#pragma unroll
    for (int j = 0; j < 2; ++j)
#pragma unroll
      for (int ks = 0; ks < 2; ++ks)
        bb[j][ks] = *(const bf16x8*)(Brd + bufo + ((j0 + j) * 2 + ks) * 512);
  };
  auto mm = [&](int i0, bf16x8 (&bb)[2][2], int j0) {
    __builtin_amdgcn_s_setprio(1);
#pragma unroll
    for (int i = 0; i < 4; ++i)
#pragma unroll
      for (int j = 0; j < 2; ++j)
#pragma unroll
        for (int ks = 0; ks < 2; ++ks)
          acc[i0 + i][j0 + j] = MFMA16(a[i][ks], bb[j][ks], acc[i0 + i][j0 + j]);
    __builtin_amdgcn_s_setprio(0);
  };

  // prologue: T0 fully + T1's B halves; vmcnt(4) leaves T1.B in flight
  stageB(0, 0, 0); stageB(0, 1, 0);
  stageA(0, 0, 0); stageA(0, 1, 0);
  stageB(1, 0, 16384); stageB(1, 1, 16384);
  VBAR1();

#pragma unroll 1
  for (int it = 0; it < 8; ++it) {
    const int t1 = 2 * it + 1;
    const int t2 = it < 7 ? 2 * it + 2 : 15;  // clamped: data garbage, region safe
    const int t3 = it < 7 ? 2 * it + 3 : 15;
    // ph1
    rdA(0, 0); rdB(0, 0, bA);
    stageA(t1, 0, 16384);
    BAR1(); mm(0, bA, 0); BAR2();
    // ph2
    rdB(0, 2, bB);
    stageA(t1, 1, 16384);
    BAR1(); mm(0, bB, 2); BAR2();
    // ph3
    rdA(0, 4);
    stageB(t2, 0, 0);
    BAR1(); mm(4, bA, 0); BAR2();
    // ph4
    stageB(t2, 1, 0);
    VBAR1(); mm(4, bB, 2); BAR2();
    // ph5
    rdA(16384, 0); rdB(16384, 0, bA);
    stageA(t2, 0, 0);
    BAR1(); mm(0, bA, 0); BAR2();
    // ph6
    rdB(16384, 2, bB);
    stageA(t2, 1, 0);
    BAR1(); mm(0, bB, 2); BAR2();
    // ph7
    rdA(16384, 4);
    stageB(t3, 0, 16384);
    BAR1(); mm(4, bA, 0); BAR2();
    // ph8
    stageB(t3, 1, 16384);
    VBAR1(); mm(4, bB, 2); BAR2();
  }
  WAITBAR(0);  // drain tail GLLs; LDS free for epilogue scratch

  // ---- epilogue: wave cols = n0 + wc*64 (one tensor, one head) ----
  const int gcw = n0 + wc * 64;
  const int which = gcw >> 10;
  const int h = (gcw & 1023) >> 6;
  const int rowb = m0 + wr * 128;
  if (which == 2) {
    // V: packed bf16x4 stores into vt[bh][d][n]
#pragma unroll
    for (int i = 0; i < 8; ++i) {
      int gm = rowb + i * 16 + quad * 4;
      int b = gm >> 10, n = gm & 1023;
      __bf16* vb = vo + ((long)(b * 16 + h) * 64) * 1024 + n;
#pragma unroll
      for (int j = 0; j < 4; ++j) {
        int dd = j * 16 + l15;
        bf16x4 pv = {(__bf16)acc[i][j][0], (__bf16)acc[i][j][1],
                     (__bf16)acc[i][j][2], (__bf16)acc[i][j][3]};
        *(bf16x4*)(vb + (long)dd * 1024) = pv;
      }
    }
  } else {
    // Q/K: per-wave LDS transpose -> 16B coalesced stores
    __bf16* dst = (which == 0) ? qo : ko;
    const float scl = (which == 0) ? QSCALE : 1.0f;
    float* T = (float*)LDS + w * 1088;  // [16][68] f32 per wave
#pragma unroll
    for (int i = 0; i < 8; ++i) {
#pragma unroll
      for (int j = 0; j < 4; ++j)
#pragma unroll
        for (int r = 0; r < 4; ++r)
          T[(quad * 4 + r) * 68 + j * 16 + l15] = acc[i][j][r];
      const float* Tr = T + l15 * 68 + quad * 16;
      f32x4 c0 = *(const f32x4*)(Tr);
      f32x4 c1 = *(const f32x4*)(Tr + 4);
      f32x4 c2 = *(const f32x4*)(Tr + 8);
      f32x4 c3 = *(const f32x4*)(Tr + 12);
      int gm = rowb + i * 16 + l15;
      int b = gm >> 10, n = gm & 1023;
      __bf16* p = dst + ((long)((b * 16 + h) * 1024 + n)) * 64 + quad * 16;
      bf16x8 o0 = {(__bf16)(c0[0] * scl), (__bf16)(c0[1] * scl),
                   (__bf16)(c0[2] * scl), (__bf16)(c0[3] * scl),
                   (__bf16)(c1[0] * scl), (__bf16)(c1[1] * scl),
                   (__bf16)(c1[2] * scl), (__bf16)(c1[3] * scl)};
      bf16x8 o1 = {(__bf16)(c2[0] * scl), (__bf16)(c2[1] * scl),
                   (__bf16)(c2[2] * scl), (__bf16)(c2[3] * scl),
                   (__bf16)(c3[0] * scl), (__bf16)(c3[1] * scl),
                   (__bf16)(c3[2] * scl), (__bf16)(c3[3] * scl)};
      *(bf16x8*)p = o0;
      *(bf16x8*)(p + 8) = o1;
    }
  }
}

// ---------------- GEMM: 128x128 tile (kept for out-proj) ----------------
__global__ __launch_bounds__(256) void gemm_bt_kernel(
    const __bf16* __restrict__ A, const __bf16* __restrict__ Bt, int mode, int nxg,
    __bf16* __restrict__ qo, __bf16* __restrict__ ko, __bf16* __restrict__ vo,
    float* __restrict__ outp, const float* __restrict__ bias) {
  __shared__ __bf16 LDS[3][2][4096];  // [buf][A/B][128*32] = 48 KiB
  const int tid = threadIdx.x;
  const int id = blockIdx.x;
  const int xcd = id & 7, s = id >> 3;
  const int bx = xcd * nxg + (nxg == 3 ? s % 3 : 0);
  const int by = (nxg == 3 ? s / 3 : s);
  const int m0 = by * 128, n0 = bx * 128;
  const int w = tid >> 6, lane = tid & 63;
  const int quad = lane >> 4, l15 = lane & 15;
  const int wm = (w >> 1) * 64, wn = (w & 1) * 64;
  f32x4 acc[4][4] = {};
  const int sr = tid >> 2;
  const int sc = (tid & 3) * 8;
  const __bf16* ag = A + (m0 + sr) * 1024 + sc;
  const __bf16* bg = Bt + (n0 + sr) * 1024 + sc;

  auto stage = [&](int T, int b) {
    const int kk = T * 32;
    GLL(ag + kk,             &LDS[b][0][0] + w * 512);
    GLL(ag + 64 * 1024 + kk, &LDS[b][0][0] + 2048 + w * 512);
    GLL(bg + kk,             &LDS[b][1][0] + w * 512);
    GLL(bg + 64 * 1024 + kk, &LDS[b][1][0] + 2048 + w * 512);
  };
  auto compute = [&](int b) {
    const __bf16* Asb = &LDS[b][0][0];
    const __bf16* Bsb = &LDS[b][1][0];
    bf16x8 af[4], bfr[4];
#pragma unroll
    for (int i = 0; i < 4; ++i)
      af[i] = *(const bf16x8*)(Asb + (wm + i * 16 + l15) * 32 + quad * 8);
#pragma unroll
    for (int j = 0; j < 4; ++j)
      bfr[j] = *(const bf16x8*)(Bsb + (wn + j * 16 + l15) * 32 + quad * 8);
#pragma unroll
    for (int i = 0; i < 4; ++i)
#pragma unroll
      for (int j = 0; j < 4; ++j)
        acc[i][j] = MFMA16(af[i], bfr[j], acc[i][j]);
  };

  stage(0, 0);
  stage(1, 1);
  WAITBAR(4);
  for (int g = 0; g < 10; ++g) {
    const int t = g * 3;
    stage(t + 2, 2); compute(0); WAITBAR(4);
    stage(t + 3, 0); compute(1); WAITBAR(4);
    stage(t + 4, 1); compute(2); WAITBAR(4);
  }
  compute(0);
  asm volatile("s_waitcnt vmcnt(0) lgkmcnt(0)\n\ts_barrier" ::: "memory");
  compute(1);
  __syncthreads();

  const int gcw = n0 + wn;
  float* T = (float*)(&LDS[0][0][0]) + w * 1088;
  if (mode == 0) {
    const int which = gcw >> 10;
    const int h = (gcw & 1023) >> 6;
    if (which == 2) {
#pragma unroll
      for (int i = 0; i < 4; ++i) {
        int gm = m0 + wm + i * 16 + quad * 4;
        int b = gm >> 10, n = gm & 1023;
        __bf16* vb = vo + ((long)(b * 16 + h) * 64) * 1024 + n;
#pragma unroll
        for (int j = 0; j < 4; ++j) {
          int dd = j * 16 + l15;
          bf16x4 pv = {(__bf16)acc[i][j][0], (__bf16)acc[i][j][1],
                       (__bf16)acc[i][j][2], (__bf16)acc[i][j][3]};
          *(bf16x4*)(vb + (long)dd * 1024) = pv;
        }
      }
    } else {
      __bf16* dst = (which == 0) ? qo : ko;
      const float scl = (which == 0) ? QSCALE : 1.0f;
#pragma unroll
      for (int i = 0; i < 4; ++i) {
#pragma unroll
        for (int j = 0; j < 4; ++j)
#pragma unroll
          for (int r = 0; r < 4; ++r)
            T[(quad * 4 + r) * 68 + j * 16 + l15] = acc[i][j][r];
        const float* Tr = T + l15 * 68 + quad * 16;
        f32x4 c0 = *(const f32x4*)(Tr);
        f32x4 c1 = *(const f32x4*)(Tr + 4);
        f32x4 c2 = *(const f32x4*)(Tr + 8);
        f32x4 c3 = *(const f32x4*)(Tr + 12);
        int gm = m0 + wm + i * 16 + l15;
        int b = gm >> 10, n = gm & 1023;
        __bf16* p = dst + ((long)((b * 16 + h) * 1024 + n)) * 64 + quad * 16;
        bf16x8 o0 = {(__bf16)(c0[0] * scl), (__bf16)(c0[1] * scl),
                     (__bf16)(c0[2] * scl), (__bf16)(c0[3] * scl),
                     (__bf16)(c1[0] * scl), (__bf16)(c1[1] * scl),
                     (__bf16)(c1[2] * scl), (__bf16)(c1[3] * scl)};
        bf16x8 o1 = {(__bf16)(c2[0] * scl), (__bf16)(c2[1] * scl),
                     (__bf16)(c2[2] * scl), (__bf16)(c2[3] * scl),
                     (__bf16)(c3[0] * scl), (__bf16)(c3[1] * scl),
                     (__bf16)(c3[2] * scl), (__bf16)(c3[3] * scl)};
        *(bf16x8*)p = o0;
        *(bf16x8*)(p + 8) = o1;
      }
    }
  } else {
    const int cb = gcw;
    f32x4 bv[4];
#pragma unroll
    for (int c = 0; c < 4; ++c)
      bv[c] = *(const f32x4*)(bias + cb + quad * 16 + c * 4);
#pragma unroll
    for (int i = 0; i < 4; ++i) {
#pragma unroll
      for (int j = 0; j < 4; ++j)
#pragma unroll
        for (int r = 0; r < 4; ++r)
          T[(quad * 4 + r) * 68 + j * 16 + l15] = acc[i][j][r];
      const float* Tr = T + l15 * 68 + quad * 16;
      int gm = m0 + wm + i * 16 + l15;
      float* p = outp + (long)gm * 1024 + cb + quad * 16;
#pragma unroll
      for (int c = 0; c < 4; ++c) {
        f32x4 v = *(const f32x4*)(Tr + c * 4);
        v += bv[c];
        *(f32x4*)(p + c * 4) = v;
      }
    }
  }
}

// ---------------- attention, S^T formulation, no-max exp2 softmax ----------------
__global__ __launch_bounds__(256, 4) void attn_kernel(
    const __bf16* __restrict__ q, const __bf16* __restrict__ k,
    const __bf16* __restrict__ vt, __bf16* __restrict__ ao) {
  __shared__ __bf16 KV[2][128 * 64];  // [0]=Ks [j][d] swz, [1]=Vs [d][j] swz; epilogue f32 scratch
  __shared__ __bf16 Ps[4][32 * 32];   // per-wave P quarter [i32][j32]
  __bf16* const Ks = KV[0];
  __bf16* const Vs = KV[1];
  const int tid = threadIdx.x;
  const int bh = blockIdx.x & 127, qt = blockIdx.x >> 7;
  const int w = tid >> 6, lane = tid & 63;
  const int quad = lane >> 4, l15 = lane & 15;
  const int qrow = qt * 128 + w * 32;
  const __bf16* qb = q + (bh * 1024 + qrow) * 64;
  bf16x8 qf[2][2];
#pragma unroll
  for (int f = 0; f < 2; ++f) {
    qf[f][0] = *(const bf16x8*)(qb + (f * 16 + l15) * 64 + quad * 8);
    qf[f][1] = *(const bf16x8*)(qb + (f * 16 + l15) * 64 + 32 + quad * 8);
  }
  f32x4 o[2][4] = {};
  float rs0 = 0.f, rs1 = 0.f;
  const int krow = tid >> 3, kg8 = tid & 7;
  const __bf16* kg = k + (bh * 1024 + krow) * 64 + kg8 * 8;
  const int ksw = (kg8 ^ (krow & 7)) * 8;
  const int vrow = tid >> 2, vg4 = tid & 3;
  const __bf16* vg = vt + (bh * 64 + vrow) * 1024 + vg4 * 8;
  const int kfs0 = (quad ^ (l15 & 7)) * 8;
  const int kfs1 = ((4 + quad) ^ (l15 & 7)) * 8;
  __bf16* const pw = Ps[w];
  const int psw = quad ^ (l15 & 3);

  bf16x8 kvr[4], vvr[4];
#pragma unroll
  for (int p = 0; p < 4; ++p) kvr[p] = *(const bf16x8*)(kg + (p * 32) * 64);
#pragma unroll
  for (int p = 0; p < 4; ++p) vvr[p] = *(const bf16x8*)(vg + p * 32);

  for (int jt = 0; jt < 8; ++jt) {
    __syncthreads();
#pragma unroll
    for (int p = 0; p < 4; ++p)
      *(bf16x8*)(Ks + (krow + p * 32) * 64 + ksw) = kvr[p];
#pragma unroll
    for (int p = 0; p < 4; ++p)
      *(bf16x8*)(Vs + vrow * 128 + (((p * 4 + vg4) ^ (vrow & 15)) * 8)) = vvr[p];
    __syncthreads();
    if (jt < 7) {
      const int j0n = (jt + 1) * 128;
#pragma unroll
      for (int p = 0; p < 4; ++p) kvr[p] = *(const bf16x8*)(kg + (j0n + p * 32) * 64);
#pragma unroll
      for (int p = 0; p < 4; ++p) vvr[p] = *(const bf16x8*)(vg + j0n + p * 32);
    }
#pragma unroll
    for (int Q = 0; Q < 4; ++Q) {
#pragma unroll
      for (int tl = 0; tl < 2; ++tl) {
        const int t = 2 * Q + tl;
        const __bf16* kr = Ks + (t * 16 + l15) * 64;
        bf16x8 kf0 = *(const bf16x8*)(kr + kfs0);
        bf16x8 kf1 = *(const bf16x8*)(kr + kfs1);
        f32x4 z0 = {}, z1 = {};
        __builtin_amdgcn_s_setprio(1);
        z0 = MFMA16(kf0, qf[0][0], z0);
        z0 = MFMA16(kf1, qf[0][1], z0);
        z1 = MFMA16(kf0, qf[1][0], z1);
        z1 = MFMA16(kf1, qf[1][1], z1);
        __builtin_amdgcn_s_setprio(0);
        const float p00 = __builtin_amdgcn_exp2f(z0[0]), p01 = __builtin_amdgcn_exp2f(z0[1]);
        const float p02 = __builtin_amdgcn_exp2f(z0[2]), p03 = __builtin_amdgcn_exp2f(z0[3]);
        const float p10 = __builtin_amdgcn_exp2f(z1[0]), p11 = __builtin_amdgcn_exp2f(z1[1]);
        const float p12 = __builtin_amdgcn_exp2f(z1[2]), p13 = __builtin_amdgcn_exp2f(z1[3]);
        rs0 += (p00 + p01) + (p02 + p03);
        rs1 += (p10 + p11) + (p12 + p13);
        const int g = (2 * tl + (quad >> 1)) ^ (l15 & 3);
        bf16x4 pa = {(__bf16)p00, (__bf16)p01, (__bf16)p02, (__bf16)p03};
        bf16x4 pb = {(__bf16)p10, (__bf16)p11, (__bf16)p12, (__bf16)p13};
        *(bf16x4*)(pw + l15 * 32 + g * 8 + (quad & 1) * 4) = pa;
        *(bf16x4*)(pw + (16 + l15) * 32 + g * 8 + (quad & 1) * 4) = pb;
      }
      bf16x8 pf0 = *(const bf16x8*)(pw + l15 * 32 + psw * 8);
      bf16x8 pf1 = *(const bf16x8*)(pw + (16 + l15) * 32 + psw * 8);
      __builtin_amdgcn_s_setprio(1);
#pragma unroll
      for (int dt = 0; dt < 4; ++dt) {
        bf16x8 vf = *(const bf16x8*)(Vs + (dt * 16 + l15) * 128 + (((Q * 4 + quad) ^ l15) * 8));
        o[0][dt] = MFMA16(pf0, vf, o[0][dt]);
        o[1][dt] = MFMA16(pf1, vf, o[1][dt]);
      }
      __builtin_amdgcn_s_setprio(0);
    }
  }
  rs0 += __shfl_xor(rs0, 16); rs0 += __shfl_xor(rs0, 32);
  rs1 += __shfl_xor(rs1, 16); rs1 += __shfl_xor(rs1, 32);
  __syncthreads();
  float* const T = (float*)KV + w * 1088;
  const int b = bh >> 4, h = bh & 15;
  const int rr = lane >> 3, c8 = lane & 7;
#pragma unroll
  for (int f = 0; f < 2; ++f) {
    const float rsf = f ? rs1 : rs0;
#pragma unroll
    for (int dt = 0; dt < 4; ++dt)
#pragma unroll
      for (int r = 0; r < 4; ++r)
        T[(quad * 4 + r) * 68 + dt * 16 + l15] = o[f][dt][r];
#pragma unroll
    for (int h2 = 0; h2 < 2; ++h2) {
      const int row = h2 * 8 + rr;
      const float inv = 1.0f / __shfl(rsf, row);
      const float* Tr = T + row * 68 + c8 * 8;
      const f32x4 a0 = *(const f32x4*)(Tr);
      const f32x4 a1 = *(const f32x4*)(Tr + 4);
      bf16x8 ov = {(__bf16)(a0[0] * inv), (__bf16)(a0[1] * inv),
                   (__bf16)(a0[2] * inv), (__bf16)(a0[3] * inv),
                   (__bf16)(a1[0] * inv), (__bf16)(a1[1] * inv),
                   (__bf16)(a1[2] * inv), (__bf16)(a1[3] * inv)};
      const long grow = (long)b * 1024 + qrow + f * 16 + row;
      *(bf16x8*)(ao + grow * 1024 + h * 64 + c8 * 8) = ov;
    }
  }
}

// ---------------- launch ----------------
extern "C" void kernel_launch(void* const* d_in, const int* in_sizes, int n_in,
                              void* d_out, int out_size, void* d_ws, size_t ws_size,
                              hipStream_t stream) {
  const float* x = (const float*)d_in[0];      // [8192,1024]
  const float* w_qkv = (const float*)d_in[1];  // [1024,3072]
  const float* w_out = (const float*)d_in[2];  // [1024,1024]
  const float* b_out = (const float*)d_in[3];  // [1024]
  float* out = (float*)d_out;

  char* ws = (char*)d_ws;
  __bf16* xb    = (__bf16*)(ws);                 // 16 MiB
  __bf16* wqkvt = (__bf16*)(ws + 16777216);      // 6 MiB
  __bf16* woutt = (__bf16*)(ws + 23068672);      // 2 MiB
  __bf16* qw    = (__bf16*)(ws + 25165824);
  __bf16* kw    = (__bf16*)(ws + 41943040);
  __bf16* vw    = (__bf16*)(ws + 58720256);      // end = 75497472
  __bf16* ao    = xb;  // alias: xb dead after QKV GEMM

  cast_x_kernel<<<8192, 256, 0, stream>>>(x, xb);
  transpose_cast_kernel<<<dim3(96, 32), dim3(32, 8), 0, stream>>>(w_qkv, wqkvt, 1024, 3072);
  transpose_cast_kernel<<<dim3(32, 32), dim3(32, 8), 0, stream>>>(w_out, woutt, 1024, 1024);
  gemm256_qkv<<<384, 512, 0, stream>>>(xb, wqkvt, qw, kw, vw);
  attn_kernel<<<1024, 256, 0, stream>>>(qw, kw, vw, ao);
  gemm_bt_kernel<<<512, 256, 0, stream>>>(ao, woutt, 1, 1, nullptr, nullptr, nullptr, out, b_out);
}